// Round 1
// baseline (459.729 us; speedup 1.0000x reference)
//
#include <hip/hip_runtime.h>

typedef _Float16 f16;
typedef _Float16 f16x8 __attribute__((ext_vector_type(8)));
typedef float f32x4 __attribute__((ext_vector_type(4)));

#define LOG2E 1.44269504088896340736f
#define CDIM 256
#define NPIX 4096
#define XS_STRIDE 264   // 256 + 8 f16 pad: keeps 16B row alignment, breaks pow-2 bank stride
#define KS_STRIDE 264
#define VS_STRIDE 72    // 64 + 8
#define PS_STRIDE 72
#define OS_STRIDE 261   // fp32 epilogue stride (odd -> conflict-free column reads)

// ---------------- kernel 0: weights fp32 -> fp16 (Wq folded with log2e) ----------------
__global__ void convert_w_kernel(const float* __restrict__ Wq, const float* __restrict__ Wk,
                                 const float* __restrict__ Wv,
                                 f16* __restrict__ Wq_h, f16* __restrict__ Wk_h,
                                 f16* __restrict__ Wv_h) {
    int i = blockIdx.x * 256 + threadIdx.x;   // 65536 elements each
    Wq_h[i] = (f16)(Wq[i] * LOG2E);
    Wk_h[i] = (f16)Wk[i];
    Wv_h[i] = (f16)Wv[i];
}

// ---------------- kernel 1: q/k/v projections via MFMA ----------------
// outputs: qT,kT as [B][N][C] fp16 (row=pixel, col=channel); v as [B][C][N] fp16
__global__ __launch_bounds__(256, 2)
void proj_kernel(const float* __restrict__ x, const float* __restrict__ attr,
                 const f16* __restrict__ Wq_h, const float* __restrict__ bq,
                 const f16* __restrict__ Wk_h, const float* __restrict__ bk,
                 const f16* __restrict__ Wv_h, const float* __restrict__ bv,
                 f16* __restrict__ qT, f16* __restrict__ kT, f16* __restrict__ vW) {
    __shared__ __align__(16) f16 Xs[64 * XS_STRIDE];
    __shared__ __align__(16) f16 As[64 * XS_STRIDE];

    const int b  = blockIdx.x & 7;
    const int i0 = (blockIdx.x >> 3) * 64;
    const int t  = threadIdx.x;
    const int w = t >> 6, lane = t & 63, l15 = lane & 15, quad = lane >> 4;

    // stage transposed tiles: Xs[i][c] = x[b][c][i0+i]  (coalesced global reads)
    {
        const float* xb = x    + (size_t)b * CDIM * NPIX + i0;
        const float* ab = attr + (size_t)b * CDIM * NPIX + i0;
#pragma unroll 4
        for (int rep = 0; rep < 64; ++rep) {
            int flat = t + rep * 256;
            int c = flat >> 6, i = flat & 63;
            Xs[i * XS_STRIDE + c] = (f16)xb[(size_t)c * NPIX + i];
            As[i * XS_STRIDE + c] = (f16)ab[(size_t)c * NPIX + i];
        }
    }
    __syncthreads();

    // preload A-frags for this wave's 16-row strip (rows 16w..16w+15)
    f16x8 xa[8], aa[8];
    {
        const f16* xr = &Xs[(16 * w + l15) * XS_STRIDE + quad * 8];
        const f16* ar = &As[(16 * w + l15) * XS_STRIDE + quad * 8];
#pragma unroll
        for (int ks = 0; ks < 8; ++ks) {
            xa[ks] = *(const f16x8*)(xr + ks * 32);
            aa[ks] = *(const f16x8*)(ar + ks * 32);
        }
    }

    // Q = Xs * Wq^T  [i][c],  K = As * Wk^T  [i][c]
#pragma unroll 1
    for (int ct = 0; ct < 16; ++ct) {
        f32x4 accq = {0.f, 0.f, 0.f, 0.f}, acck = {0.f, 0.f, 0.f, 0.f};
        const f16* wqp = Wq_h + (ct * 16 + l15) * CDIM + quad * 8;
        const f16* wkp = Wk_h + (ct * 16 + l15) * CDIM + quad * 8;
#pragma unroll
        for (int ks = 0; ks < 8; ++ks) {
            accq = __builtin_amdgcn_mfma_f32_16x16x32_f16(xa[ks], *(const f16x8*)(wqp + ks * 32), accq, 0, 0, 0);
            acck = __builtin_amdgcn_mfma_f32_16x16x32_f16(aa[ks], *(const f16x8*)(wkp + ks * 32), acck, 0, 0, 0);
        }
        const int cc = ct * 16 + l15;
        const float biasq = bq[cc] * LOG2E;
        const float biask = bk[cc];
#pragma unroll
        for (int r = 0; r < 4; ++r) {
            int i = i0 + 16 * w + quad * 4 + r;   // D row = quad*4+reg
            qT[((size_t)b * NPIX + i) * CDIM + cc] = (f16)(accq[r] + biasq);
            kT[((size_t)b * NPIX + i) * CDIM + cc] = (f16)(acck[r] + biask);
        }
    }

    // V = Wv * As^T  -> [c][j]
#pragma unroll 1
    for (int mt = 0; mt < 4; ++mt) {
        const int ctile = w * 4 + mt;
        f16x8 wa[8];
        const f16* wvp = Wv_h + (ctile * 16 + l15) * CDIM + quad * 8;
#pragma unroll
        for (int ks = 0; ks < 8; ++ks) wa[ks] = *(const f16x8*)(wvp + ks * 32);
        float bias4[4];
#pragma unroll
        for (int r = 0; r < 4; ++r) bias4[r] = bv[ctile * 16 + quad * 4 + r];
#pragma unroll 1
        for (int nt = 0; nt < 4; ++nt) {
            f32x4 acc = {0.f, 0.f, 0.f, 0.f};
            const f16* ap = &As[(nt * 16 + l15) * XS_STRIDE + quad * 8];
#pragma unroll
            for (int ks = 0; ks < 8; ++ks)
                acc = __builtin_amdgcn_mfma_f32_16x16x32_f16(wa[ks], *(const f16x8*)(ap + ks * 32), acc, 0, 0, 0);
#pragma unroll
            for (int r = 0; r < 4; ++r) {
                int c = ctile * 16 + quad * 4 + r;   // D row = c-within-output
                int j = i0 + nt * 16 + l15;          // D col = j
                vW[((size_t)b * CDIM + c) * NPIX + j] = (f16)(acc[r] + bias4[r]);
            }
        }
    }
}

// ---------------- kernel 2: flash attention + residual ----------------
__global__ __launch_bounds__(256, 2)
void attn_kernel(const f16* __restrict__ qT, const f16* __restrict__ kT,
                 const f16* __restrict__ vW, const float* __restrict__ x,
                 float* __restrict__ out) {
    __shared__ __align__(16) unsigned char smem[79872];
    f16* Ks = (f16*)smem;                         // 64 x 264 x2B = 33792
    f16* Vs = (f16*)(smem + 33792);               // 256 x 72 x2B = 36864
    f16* Ps = (f16*)(smem + 33792 + 36864);       // 64 x 72 x2B  = 9216
    float* Os = (float*)smem;                     // epilogue overlay: 64 x 261 x4B = 66816

    const int b  = blockIdx.x & 7;                // batch -> XCD pinning for K/V L2 reuse
    const int i0 = (blockIdx.x >> 3) * 64;
    const int t  = threadIdx.x;
    const int w = t >> 6, lane = t & 63, l15 = lane & 15, quad = lane >> 4;

    // Q fragments live in registers: wave strip rows 16w..16w+15, all 256 channels
    f16x8 qf[8];
    {
        const f16* qp = qT + ((size_t)b * NPIX + i0 + 16 * w + l15) * CDIM + quad * 8;
#pragma unroll
        for (int ks = 0; ks < 8; ++ks) qf[ks] = *(const f16x8*)(qp + ks * 32);
    }

    f32x4 o[16];
#pragma unroll
    for (int ct = 0; ct < 16; ++ct) o[ct] = (f32x4){0.f, 0.f, 0.f, 0.f};
    float m[4], l[4];
#pragma unroll
    for (int r = 0; r < 4; ++r) { m[r] = -3.0e38f; l[r] = 0.0f; }

    const f16* kb = kT + (size_t)b * NPIX * CDIM;
    const f16* vb = vW + (size_t)b * CDIM * NPIX;

    for (int jt = 0; jt < 64; ++jt) {
        const int j0 = jt * 64;
        __syncthreads();   // previous iteration done reading Ks/Vs
        {
            const f16* kbase = kb + (size_t)j0 * CDIM;
#pragma unroll
            for (int rep = 0; rep < 8; ++rep) {     // K tile: 64 rows x 256 f16
                int ch = t + rep * 256;
                int row = ch >> 5, col = (ch & 31) * 8;
                *(f16x8*)(Ks + row * KS_STRIDE + col) = *(const f16x8*)(kbase + row * CDIM + col);
            }
            const f16* vbase = vb + j0;
#pragma unroll
            for (int rep = 0; rep < 8; ++rep) {     // V tile: 256 rows x 64 f16
                int ch = t + rep * 256;
                int row = ch >> 3, col = (ch & 7) * 8;
                *(f16x8*)(Vs + row * VS_STRIDE + col) = *(const f16x8*)(vbase + (size_t)row * NPIX + col);
            }
        }
        __syncthreads();

        // S strip (16 rows x 64 j) = Q K^T  (log2-domain logits)
        f32x4 s[4];
#pragma unroll
        for (int nt = 0; nt < 4; ++nt) {
            f32x4 acc = {0.f, 0.f, 0.f, 0.f};
            const f16* kp = Ks + (nt * 16 + l15) * KS_STRIDE + quad * 8;
#pragma unroll
            for (int ks = 0; ks < 8; ++ks)
                acc = __builtin_amdgcn_mfma_f32_16x16x32_f16(qf[ks], *(const f16x8*)(kp + ks * 32), acc, 0, 0, 0);
            s[nt] = acc;
        }

        // online softmax (rows r: 16w + quad*4 + r)
        float mnew[4], alpha[4];
#pragma unroll
        for (int r = 0; r < 4; ++r) {
            float mx = fmaxf(fmaxf(s[0][r], s[1][r]), fmaxf(s[2][r], s[3][r]));
            mx = fmaxf(mx, __shfl_xor(mx, 1));
            mx = fmaxf(mx, __shfl_xor(mx, 2));
            mx = fmaxf(mx, __shfl_xor(mx, 4));
            mx = fmaxf(mx, __shfl_xor(mx, 8));
            mnew[r]  = fmaxf(m[r], mx);
            alpha[r] = __builtin_amdgcn_exp2f(m[r] - mnew[r]);
            m[r] = mnew[r];
        }
        float rs[4] = {0.f, 0.f, 0.f, 0.f};
#pragma unroll
        for (int nt = 0; nt < 4; ++nt)
#pragma unroll
            for (int r = 0; r < 4; ++r) {
                float p = __builtin_amdgcn_exp2f(s[nt][r] - mnew[r]);
                s[nt][r] = p;
                rs[r] += p;
            }
#pragma unroll
        for (int r = 0; r < 4; ++r) {
            float v = rs[r];
            v += __shfl_xor(v, 1); v += __shfl_xor(v, 2);
            v += __shfl_xor(v, 4); v += __shfl_xor(v, 8);
            l[r] = l[r] * alpha[r] + v;
        }

        // P -> LDS (C/D layout -> A layout), wave-private rows, no barrier needed
#pragma unroll
        for (int nt = 0; nt < 4; ++nt)
#pragma unroll
            for (int r = 0; r < 4; ++r)
                Ps[(16 * w + quad * 4 + r) * PS_STRIDE + nt * 16 + l15] = (f16)s[nt][r];

        // rescale O by alpha
#pragma unroll
        for (int ct = 0; ct < 16; ++ct)
#pragma unroll
            for (int r = 0; r < 4; ++r) o[ct][r] *= alpha[r];

        // O += P V : A = P[i][j], B = Vs[c][j]
        const f16* pp = Ps + (16 * w + l15) * PS_STRIDE + quad * 8;
        f16x8 pa0 = *(const f16x8*)(pp);
        f16x8 pa1 = *(const f16x8*)(pp + 32);
#pragma unroll
        for (int ct = 0; ct < 16; ++ct) {
            const f16* vp = Vs + (ct * 16 + l15) * VS_STRIDE + quad * 8;
            o[ct] = __builtin_amdgcn_mfma_f32_16x16x32_f16(pa0, *(const f16x8*)(vp), o[ct], 0, 0, 0);
            o[ct] = __builtin_amdgcn_mfma_f32_16x16x32_f16(pa1, *(const f16x8*)(vp + 32), o[ct], 0, 0, 0);
        }
    }

    // epilogue: O/l -> LDS transpose -> coalesced residual-add store
    __syncthreads();
#pragma unroll
    for (int r = 0; r < 4; ++r) {
        float inv = 1.0f / l[r];
#pragma unroll
        for (int ct = 0; ct < 16; ++ct)
            Os[(16 * w + quad * 4 + r) * OS_STRIDE + ct * 16 + l15] = o[ct][r] * inv;
    }
    __syncthreads();
    {
        const float* xb = x + (size_t)b * CDIM * NPIX + i0;
        float* ob = out + (size_t)b * CDIM * NPIX + i0;
#pragma unroll 4
        for (int rep = 0; rep < 64; ++rep) {
            int flat = t + rep * 256;
            int c = flat >> 6, il = flat & 63;
            ob[(size_t)c * NPIX + il] = Os[il * OS_STRIDE + c] + xb[(size_t)c * NPIX + il];
        }
    }
}

extern "C" void kernel_launch(void* const* d_in, const int* in_sizes, int n_in,
                              void* d_out, int out_size, void* d_ws, size_t ws_size,
                              hipStream_t stream) {
    const float* x    = (const float*)d_in[0];
    const float* attr = (const float*)d_in[1];
    const float* Wq   = (const float*)d_in[2];
    const float* bq   = (const float*)d_in[3];
    const float* Wk   = (const float*)d_in[4];
    const float* bk   = (const float*)d_in[5];
    const float* Wv   = (const float*)d_in[6];
    const float* bv   = (const float*)d_in[7];
    float* out = (float*)d_out;

    // workspace layout (needs ~51 MB)
    char* ws = (char*)d_ws;
    const size_t qkv_bytes = (size_t)8 * NPIX * CDIM * sizeof(f16);  // 16 MB each
    f16* qT   = (f16*)ws;
    f16* kT   = (f16*)(ws + qkv_bytes);
    f16* vW   = (f16*)(ws + 2 * qkv_bytes);
    f16* Wq_h = (f16*)(ws + 3 * qkv_bytes);
    f16* Wk_h = Wq_h + 65536;
    f16* Wv_h = Wk_h + 65536;

    convert_w_kernel<<<256, 256, 0, stream>>>(Wq, Wk, Wv, Wq_h, Wk_h, Wv_h);
    proj_kernel<<<512, 256, 0, stream>>>(x, attr, Wq_h, bq, Wk_h, bk, Wv_h, bv, qT, kT, vW);
    attn_kernel<<<512, 256, 0, stream>>>(qT, kT, vW, x, out);
}